// Round 3
// baseline (289.048 us; speedup 1.0000x reference)
//
#include <hip/hip_runtime.h>
#include <math.h>

// warpLayer: out[n,h,w,0:8] = bilinear(weight, angle-coords(image)) * 5e-4
//            out[n,h,w,8:12] = image[n,h,w,:]
// image: (16,512,512,4) fp32 ; weight: (256,256,8) fp32 ; out: (16,512,512,12) fp32
//
// R3: wave-autonomous, barrier-free hot path.
//  - Each wave owns 64 consecutive pixels. Gather cooperation via __shfl
//    (8 lanes per pixel -> two 64B weight-row requests), corner factors
//    applied in-register, blended via __shfl_xor butterfly. No gather LDS.
//  - 12KB LDS used only to transpose results for 3 fully-coalesced stores.
//  - One __syncthreads per block; occupancy limited only by HW wave cap.

#define GW 256

__device__ __forceinline__ float4 f4_mad(float4 a, float s, float4 acc) {
    acc.x = fmaf(a.x, s, acc.x);
    acc.y = fmaf(a.y, s, acc.y);
    acc.z = fmaf(a.z, s, acc.z);
    acc.w = fmaf(a.w, s, acc.w);
    return acc;
}

__global__ __launch_bounds__(256) void warp_kernel(
    const float4* __restrict__ img,    // npix pixels
    const float4* __restrict__ wq,     // weight as float4: GH*GW*2 entries
    float4*       __restrict__ out,    // npix*3 float4
    int npix)
{
    __shared__ float4 stage[4 * 192];  // 12 KB: per-wave output staging

    const int t    = threadIdx.x;
    const int lane = t & 63;
    const int wv   = t >> 6;
    const int base = blockIdx.x * 256;

    const float PI        = 3.14159265358979323846f;
    const float SCALE     = 255.0f / (2.0f * PI);
    const float OUT_SCALE = 0.0005f;

    if (base + 256 > npix) {
        // tail fallback (never taken for the benchmark size)
        int p = base + t;
        if (p >= npix) return;
        float4 px = img[p];
        float c0 = (PI - atan2f(px.y, -px.x)) * SCALE;
        float c1 = (PI - atan2f(px.w, -px.z)) * SCALE;
        c0 = fminf(fmaxf(c0, 0.0f), 254.0f);
        c1 = fminf(fmaxf(c1, 0.0f), 254.0f);
        int i0 = (int)c0, j0 = (int)c1;
        float w0 = c0 - (float)i0, w1 = c1 - (float)j0;
        float f00 = (1.0f - w0) * (1.0f - w1), f10 = w0 * (1.0f - w1);
        float f01 = (1.0f - w0) * w1,          f11 = w0 * w1;
        int b00 = (i0 * GW + j0) * 2, b10 = b00 + GW * 2;
        float4 ra = make_float4(0,0,0,0), rb = make_float4(0,0,0,0);
        ra = f4_mad(wq[b00],   f00, ra); rb = f4_mad(wq[b00+1], f00, rb);
        ra = f4_mad(wq[b00+2], f01, ra); rb = f4_mad(wq[b00+3], f01, rb);
        ra = f4_mad(wq[b10],   f10, ra); rb = f4_mad(wq[b10+1], f10, rb);
        ra = f4_mad(wq[b10+2], f11, ra); rb = f4_mad(wq[b10+3], f11, rb);
        ra.x*=OUT_SCALE; ra.y*=OUT_SCALE; ra.z*=OUT_SCALE; ra.w*=OUT_SCALE;
        rb.x*=OUT_SCALE; rb.y*=OUT_SCALE; rb.z*=OUT_SCALE; rb.w*=OUT_SCALE;
        int ob = p * 3;
        out[ob] = ra; out[ob+1] = rb; out[ob+2] = px;
        return;
    }

    // ---- per-pixel coords (each lane owns one pixel) ----
    const int pw = base + wv * 64;          // wave's first pixel
    float4 px = img[pw + lane];

    float c0 = (PI - atan2f(px.y, -px.x)) * SCALE;
    float c1 = (PI - atan2f(px.w, -px.z)) * SCALE;
    c0 = fminf(fmaxf(c0, 0.0f), 254.0f);
    c1 = fminf(fmaxf(c1, 0.0f), 254.0f);
    int i0 = (int)c0, j0 = (int)c1;
    float w0 = c0 - (float)i0, w1 = c1 - (float)j0;
    int abase = i0 * (GW * 2) + j0 * 2;     // float4 index of 64B row (i0, j0..j0+1)

    float4* mystage = stage + wv * 192;
    mystage[lane * 3 + 2] = px;             // passthrough channel

    // ---- cooperative gather + in-register blend ----
    // 8 lanes per pixel: hc bit2 = di (row), bit1 = dj (col), bit0 = a/b half.
    const int hc  = lane & 7;
    const int sub = lane >> 3;
    #pragma unroll
    for (int k = 0; k < 8; k++) {
        int   p8  = (k << 3) + sub;                   // pixel index within wave
        int   ab  = __shfl(abase, p8, 64);
        float pw0 = __shfl(w0,    p8, 64);
        float pw1 = __shfl(w1,    p8, 64);
        float f0  = (hc & 4) ? pw0 : (1.0f - pw0);
        float f1  = (hc & 2) ? pw1 : (1.0f - pw1);
        float fac = f0 * f1 * OUT_SCALE;
        int   off = ((hc & 4) ? (GW * 2) : 0) + ((hc & 2) ? 2 : 0) + (hc & 1);

        float4 v = wq[ab + off];
        float rx = v.x * fac, ry = v.y * fac, rz = v.z * fac, rw = v.w * fac;

        // butterfly: sum the 4 corners; even hc -> ra, odd hc -> rb
        rx += __shfl_xor(rx, 2, 64); ry += __shfl_xor(ry, 2, 64);
        rz += __shfl_xor(rz, 2, 64); rw += __shfl_xor(rw, 2, 64);
        rx += __shfl_xor(rx, 4, 64); ry += __shfl_xor(ry, 4, 64);
        rz += __shfl_xor(rz, 4, 64); rw += __shfl_xor(rw, 4, 64);

        if (hc < 2)
            mystage[p8 * 3 + hc] = make_float4(rx, ry, rz, rw);
    }

    __syncthreads();

    // ---- 3 fully-coalesced 1KB stores per wave ----
    int ob = base * 3 + wv * 192;
    out[ob + lane]       = mystage[lane];
    out[ob + 64 + lane]  = mystage[64 + lane];
    out[ob + 128 + lane] = mystage[128 + lane];
}

extern "C" void kernel_launch(void* const* d_in, const int* in_sizes, int n_in,
                              void* d_out, int out_size, void* d_ws, size_t ws_size,
                              hipStream_t stream) {
    const float4* img = (const float4*)d_in[0];
    const float4* wq  = (const float4*)d_in[1];
    float4*       out = (float4*)d_out;

    int npix = in_sizes[0] / 4;           // 16*512*512 = 4,194,304
    int block = 256;
    int grid = (npix + block - 1) / block;

    warp_kernel<<<grid, block, 0, stream>>>(img, wq, out, npix);
}